// Round 6
// baseline (425.090 us; speedup 1.0000x reference)
//
#include <hip/hip_runtime.h>

typedef unsigned short u16;
typedef __bf16 bf16x8 __attribute__((ext_vector_type(8)));
typedef __bf16 bf16x2_t __attribute__((ext_vector_type(2)));
typedef float f32x4 __attribute__((ext_vector_type(4)));

#define AS1 __attribute__((address_space(1)))
#define AS3 __attribute__((address_space(3)))

__device__ __forceinline__ void gld16(const void* g, void* l) {
  // 16B per lane: global per-lane gather -> LDS (wave-uniform base + lane*16)
  __builtin_amdgcn_global_load_lds((const AS1 void*)g, (AS3 void*)l, 16, 0, 0);
}

__device__ __forceinline__ u16 f2bf(float f) {
  union { float f; unsigned int u; } v; v.f = f;
  unsigned int u = v.u;
  u += 0x7fffu + ((u >> 16) & 1u);
  return (u16)(u >> 16);
}
__device__ __forceinline__ float bf2f(u16 h) {
  union { unsigned int u; float f; } v; v.u = ((unsigned int)h) << 16; return v.f;
}
// pack 2 fp32 -> 2 bf16 in one HW instr where available
__device__ __forceinline__ unsigned int pk2(float a, float b) {
#if __has_builtin(__builtin_amdgcn_cvt_pk_bf16_f32)
  union { bf16x2_t v; unsigned int u; } c;
  c.v = __builtin_amdgcn_cvt_pk_bf16_f32(a, b);
  return c.u;
#else
  return (unsigned int)f2bf(a) | ((unsigned int)f2bf(b) << 16);
#endif
}
// fast GELU: v * sigmoid(v*(1.5957691 + 0.0713548*v^2)); raw v_rcp (1 instr)
__device__ __forceinline__ float gelu_f(float v) {
  float u = v * (1.5957691216f + 0.0713548163f * v * v);
  return v * __builtin_amdgcn_rcpf(1.0f + __expf(-u));
}

// ---------------- cast weights fp32 -> bf16 ----------------
// proj_w gets head-interleaved column permutation to match attn's packed stores:
// attn lane holds (d, d+16) pairs -> stored at cols (2d, 2d+1) within the head.
__global__ __launch_bounds__(256) void cast_weights(
    const float* __restrict__ w0, const float* __restrict__ w1,
    const float* __restrict__ w2, const float* __restrict__ w3,
    u16* __restrict__ o0, u16* __restrict__ o1,
    u16* __restrict__ o2, u16* __restrict__ o3) {
  int i = blockIdx.x * 256 + threadIdx.x;
  if (i < 110592) o0[i] = f2bf(w0[i]);   // qkv_w 576x192
  if (i < 36864) {                        // proj_w 192x192, k-permuted
    int n = i / 192, kp = i - n * 192;
    int h = kp >> 5, dp = kp & 31;
    int d = (dp & 1) ? ((dp >> 1) + 16) : (dp >> 1);
    o1[i] = f2bf(w1[n * 192 + h * 32 + d]);
  }
  if (i < 221184) o2[i] = f2bf(w2[i]);   // fc1_w 1152x192
  if (i < 221184) o3[i] = f2bf(w3[i]);   // fc2_w 192x1152
}

// ---------------- bias table [6][64(key m)][64(query r)]; key>=49 -> -1e30 ----
__global__ __launch_bounds__(256) void build_btab(
    const float* __restrict__ rpb, float* __restrict__ btab) {
  int id = blockIdx.x * 256 + threadIdx.x;   // 96*256 = 24576
  int head = id >> 12;
  int m = (id >> 6) & 63;
  int r = id & 63;
  float v;
  if (m >= 49) v = -1e30f;                   // key mask folds into bias
  else if (r >= 49) v = 0.0f;
  else {
    int mi = m / 7, mj = m - mi * 7;
    int ri = r / 7, rj = r - ri * 7;
    v = rpb[((ri - mi + 6) * 13 + (rj - mj + 6)) * 6 + head];
  }
  btab[id] = v;
}

// ---------------- layernorm (fp32 in, bf16 out), 1 wave per row of 192 ----------------
__global__ __launch_bounds__(256) void ln_kernel(
    const float* __restrict__ x, const float* __restrict__ g,
    const float* __restrict__ b, u16* __restrict__ out) {
  int row = blockIdx.x * 4 + (threadIdx.x >> 6);
  int lane = threadIdx.x & 63;
  const float* xr = x + (long)row * 192;
  float e0 = xr[lane], e1 = xr[lane + 64], e2 = xr[lane + 128];
  float s = e0 + e1 + e2;
  #pragma unroll
  for (int o = 1; o < 64; o <<= 1) s += __shfl_xor(s, o);
  float mean = s * (1.0f / 192.0f);
  float d0 = e0 - mean, d1 = e1 - mean, d2 = e2 - mean;
  float q = d0 * d0 + d1 * d1 + d2 * d2;
  #pragma unroll
  for (int o = 1; o < 64; o <<= 1) q += __shfl_xor(q, o);
  float rstd = rsqrtf(q * (1.0f / 192.0f) + 1e-5f);
  u16* orow = out + (long)row * 192;
  orow[lane]       = f2bf(d0 * rstd * g[lane]       + b[lane]);
  orow[lane + 64]  = f2bf(d1 * rstd * g[lane + 64]  + b[lane + 64]);
  orow[lane + 128] = f2bf(d2 * rstd * g[lane + 128] + b[lane + 128]);
}

// ---------------- MFMA GEMM (qkv / proj): out[M,N] = A[M,K] @ W[N,K]^T + bias --
// Block tile 128x96, 4 waves 2x2 (wave tile 64x48), 16x16x32 bf16 MFMA.
// K chunked by 96, staged fragment-ordered via global_load_lds width-16.
// MODE 0: store bf16. MODE 2: +resid(fp32) -> fp32.
template<int MODE>
__global__ __launch_bounds__(256, 3) void gemm_kernel(
    const u16* __restrict__ A, const u16* __restrict__ W,
    const float* __restrict__ bias, const float* __restrict__ resid,
    void* __restrict__ out, int N, int K) {
  __shared__ u16 lds[25600];           // 51,200 B (epilogue 128x100 f32 overlay)
  float* ct = (float*)lds;
  const int tid = threadIdx.x;
  const int wave = tid >> 6, lane = tid & 63;
  const int wm = wave >> 1, wn = wave & 1;
  const int quad = lane >> 4, l15 = lane & 15;
  const long bm = (long)blockIdx.x * 128;
  const int bn = blockIdx.y * 96;

  f32x4 acc[4][3] = {};
  for (int kc = 0; kc < K; kc += 96) {
    if (kc) __syncthreads();           // LDS reuse across chunks
    for (int t = wave; t < 42; t += 4) {
      int isB = t >= 24;
      int tt = isB ? t - 24 : t;
      int grp = tt / 3, kt = tt - grp * 3;
      const u16* g = isB
          ? (W + (long)(bn + grp * 16 + l15) * K + kc + kt * 32 + quad * 8)
          : (A + (bm + grp * 16 + l15) * K + kc + kt * 32 + quad * 8);
      gld16(g, &lds[(isB ? 12288 : 0) + tt * 512]);
    }
    __syncthreads();
    #pragma unroll
    for (int kt = 0; kt < 3; kt++) {
      bf16x8 af[4], bfr[3];
      #pragma unroll
      for (int mt = 0; mt < 4; mt++)
        af[mt] = *(const bf16x8*)&lds[((wm * 4 + mt) * 3 + kt) * 512 + lane * 8];
      #pragma unroll
      for (int nt = 0; nt < 3; nt++)
        bfr[nt] = *(const bf16x8*)&lds[12288 + ((wn * 3 + nt) * 3 + kt) * 512 + lane * 8];
      #pragma unroll
      for (int mt = 0; mt < 4; mt++)
        #pragma unroll
        for (int nt = 0; nt < 3; nt++)
          acc[mt][nt] = __builtin_amdgcn_mfma_f32_16x16x32_bf16(af[mt], bfr[nt], acc[mt][nt], 0, 0, 0);
    }
  }
  __syncthreads();
  // ---- epilogue: acc(+bias) -> LDS fp32 [128][100] ----
  #pragma unroll
  for (int nt = 0; nt < 3; nt++) {
    int col = wn * 48 + nt * 16 + l15;
    float bi = bias[bn + col];
    #pragma unroll
    for (int mt = 0; mt < 4; mt++) {
      int row0 = wm * 64 + mt * 16 + quad * 4;
      #pragma unroll
      for (int j = 0; j < 4; j++)
        ct[(row0 + j) * 100 + col] = acc[mt][nt][j] + bi;
    }
  }
  __syncthreads();
  // ---- coalesced writeout: 3072 float4 chunks (128 rows x 24 groups) ----
  #pragma unroll
  for (int it = 0; it < 12; it++) {
    int c = it * 256 + tid;
    int row = c / 24, i = c - row * 24;
    float4 v = *(const float4*)&ct[row * 100 + i * 4];
    long idx = (bm + row) * (long)N + bn + i * 4;
    if (MODE == 2) {
      const float4 rv = *(const float4*)(resid + idx);
      v.x += rv.x; v.y += rv.y; v.z += rv.z; v.w += rv.w;
      *(float4*)((float*)out + idx) = v;
    } else {
      uint2 pk;
      pk.x = pk2(v.x, v.y);
      pk.y = pk2(v.z, v.w);
      *(uint2*)((u16*)out + idx) = pk;
    }
  }
}

// ---------------- fused MLP: out = x2 + (gelu(hA@W1^T+b1)) @ W2^T + b2 --------
// One wave owns 32 token-rows end-to-end; hidden processed in 12 chunks of 96.
// hid^T computed via MFMA(W1-frag, hA-frag) so each lane's 4 results are
// k-consecutive -> gelu+pack -> single ds_write_b64 into wave-private LDS in
// exact fc2-A-fragment order -> conflict-free ds_read_b128 -> fc2 MFMA
// accumulate (transposed: MFMA(W2-frag, hid-frag)) into 32x192 registers.
// Zero __syncthreads, zero intermediate HBM traffic. W frags direct from
// global (L1/L2-hot: all waves read the same 442 KB).
__global__ __launch_bounds__(128, 2) void mlp_kernel(
    const u16* __restrict__ hA, const u16* __restrict__ W1,
    const float* __restrict__ b1, const u16* __restrict__ W2,
    const float* __restrict__ b2, const float* __restrict__ x2,
    float* __restrict__ out) {
  __shared__ u16 lds[2 * 3072];        // per wave: 6 frag-tiles of 512 u16
  const int tid = threadIdx.x;
  const int wave = tid >> 6, lane = tid & 63;
  const int quad = lane >> 4, l15 = lane & 15;
  u16* hx = lds + wave * 3072;
  const long R = ((long)blockIdx.x * 2 + wave) * 32;

  f32x4 acc2[2][12] = {};
  for (int nc = 0; nc < 12; nc++) {
    // ---- phase 1: hidT[c][r] = W1chunk @ hA^T ----
    f32x4 acc1[6][2] = {};
    #pragma unroll
    for (int kt = 0; kt < 6; kt++) {
      bf16x8 a0 = *(const bf16x8*)(hA + (R + l15) * 192 + kt * 32 + quad * 8);
      bf16x8 a1 = *(const bf16x8*)(hA + (R + 16 + l15) * 192 + kt * 32 + quad * 8);
      #pragma unroll
      for (int ctt = 0; ctt < 6; ctt++) {
        bf16x8 w1f = *(const bf16x8*)(W1 + (long)(nc * 96 + ctt * 16 + l15) * 192 + kt * 32 + quad * 8);
        acc1[ctt][0] = __builtin_amdgcn_mfma_f32_16x16x32_bf16(w1f, a0, acc1[ctt][0], 0, 0, 0);
        acc1[ctt][1] = __builtin_amdgcn_mfma_f32_16x16x32_bf16(w1f, a1, acc1[ctt][1], 0, 0, 0);
      }
    }
    // ---- phase 2: bias1 + gelu + pack -> LDS in fc2-A-fragment order ----
    // lane holds c = ctt*16 + quad*4 + j (j=0..3), row r = rt*16 + l15.
    #pragma unroll
    for (int ctt = 0; ctt < 6; ctt++) {
      float4 bb = *(const float4*)(b1 + nc * 96 + ctt * 16 + quad * 4);
      #pragma unroll
      for (int rt = 0; rt < 2; rt++) {
        float g0 = gelu_f(acc1[ctt][rt][0] + bb.x);
        float g1 = gelu_f(acc1[ctt][rt][1] + bb.y);
        float g2 = gelu_f(acc1[ctt][rt][2] + bb.z);
        float g3 = gelu_f(acc1[ctt][rt][3] + bb.w);
        uint2 pk;
        pk.x = pk2(g0, g1);
        pk.y = pk2(g2, g3);
        int addr = (rt * 3 + (ctt >> 1)) * 512 + ((ctt & 1) * 2 + (quad >> 1)) * 128
                 + l15 * 8 + (quad & 1) * 4;
        *(uint2*)&hx[addr] = pk;
      }
    }
    // ---- phase 3: fc2 accumulate (same-wave LDS; lgkmcnt orders it) ----
    #pragma unroll
    for (int kt2 = 0; kt2 < 3; kt2++) {
      bf16x8 h0 = *(const bf16x8*)&hx[kt2 * 512 + lane * 8];
      bf16x8 h1 = *(const bf16x8*)&hx[(3 + kt2) * 512 + lane * 8];
      #pragma unroll
      for (int nt = 0; nt < 12; nt++) {
        bf16x8 w2f = *(const bf16x8*)(W2 + (long)(nt * 16 + l15) * 1152 + nc * 96 + kt2 * 32 + quad * 8);
        acc2[0][nt] = __builtin_amdgcn_mfma_f32_16x16x32_bf16(w2f, h0, acc2[0][nt], 0, 0, 0);
        acc2[1][nt] = __builtin_amdgcn_mfma_f32_16x16x32_bf16(w2f, h1, acc2[1][nt], 0, 0, 0);
      }
    }
  }
  // ---- epilogue: lane holds out col = nt*16 + quad*4 + j, row = rt*16 + l15 ----
  #pragma unroll
  for (int nt = 0; nt < 12; nt++) {
    float4 bb = *(const float4*)(b2 + nt * 16 + quad * 4);
    #pragma unroll
    for (int rt = 0; rt < 2; rt++) {
      long idx = (R + rt * 16 + l15) * 192 + nt * 16 + quad * 4;
      float4 rv = *(const float4*)(x2 + idx);
      float4 v;
      v.x = acc2[rt][nt][0] + bb.x + rv.x;
      v.y = acc2[rt][nt][1] + bb.y + rv.y;
      v.z = acc2[rt][nt][2] + bb.z + rv.z;
      v.w = acc2[rt][nt][3] + bb.w + rv.w;
      *(float4*)(out + idx) = v;
    }
  }
}

// ---------------- MFMA windowed attention: 1 wave per (window, head) ----------------
__global__ __launch_bounds__(256) void attn_kernel(
    const u16* __restrict__ qkv, const float* __restrict__ btab,
    u16* __restrict__ attn) {
  // per-wave u16: P 64x72 = 4608 | Vt 32x72 = 2304 | rsum 64 f32 = 128
  __shared__ u16 lds[4 * 7040];   // 56,320 B
  int tid = threadIdx.x;
  int wave = tid >> 6, lane = tid & 63;
  int quad = lane >> 4, l15 = lane & 15;
  int w = blockIdx.x * 4 + wave;
  int win = w / 6, head = w - win * 6;
  int b = win >> 6, wy = (win >> 3) & 7, wx = win & 7;
  u16* lp = lds + wave * 7040;
  u16* lvt = lp + 4608;
  float* rsum = (float*)(lp + 6912);

  bf16x8 qb[4], ka[4];
  #pragma unroll
  for (int t = 0; t < 4; t++) {
    int n = t * 16 + l15;
    uint4 qv = {0, 0, 0, 0}, kv = {0, 0, 0, 0}, vv = {0, 0, 0, 0};
    if (n < 49) {
      int i = n / 7, j = n - i * 7;
      int y = wy * 7 + i + 3;  if (y >= 56) y -= 56;
      int xx = wx * 7 + j + 3; if (xx >= 56) xx -= 56;
      long base = ((long)(b * 3136 + y * 56 + xx)) * 576 + head * 32 + quad * 8;
      qv = *(const uint4*)(qkv + base);
      kv = *(const uint4*)(qkv + base + 192);
      vv = *(const uint4*)(qkv + base + 384);
    }
    qb[t] = *(const bf16x8*)&qv;
    ka[t] = *(const bf16x8*)&kv;
    const u16* vp = (const u16*)&vv;
    #pragma unroll
    for (int d = 0; d < 8; d++) lvt[(quad * 8 + d) * 72 + n] = vp[d];
  }

  f32x4 s[4][4];
  const f32x4 fz = {0.0f, 0.0f, 0.0f, 0.0f};
  #pragma unroll
  for (int tm = 0; tm < 4; tm++)
    #pragma unroll
    for (int tr = 0; tr < 4; tr++)
      s[tm][tr] = __builtin_amdgcn_mfma_f32_16x16x32_bf16(ka[tm], qb[tr], fz, 0, 0, 0);

  const float scale = 0.17677669529663687f;  // 32^-0.5
  const float* bt = btab + head * 4096;
  float mx[4] = {-1e30f, -1e30f, -1e30f, -1e30f};
  #pragma unroll
  for (int tm = 0; tm < 4; tm++) {
    int m0 = tm * 16 + quad * 4;
    #pragma unroll
    for (int tr = 0; tr < 4; tr++) {
      int r = tr * 16 + l15;
      #pragma unroll
      for (int j = 0; j < 4; j++) {
        float v = s[tm][tr][j] * scale + bt[(m0 + j) * 64 + r];
        s[tm][tr][j] = v;
        mx[tr] = fmaxf(mx[tr], v);
      }
    }
  }
  #pragma unroll
  for (int tr = 0; tr < 4; tr++) {
    mx[tr] = fmaxf(mx[tr], __shfl_xor(mx[tr], 16));
    mx[tr] = fmaxf(mx[tr], __shfl_xor(mx[tr], 32));
  }
  float sm[4] = {0.f, 0.f, 0.f, 0.f};
  #pragma unroll
  for (int tm = 0; tm < 4; tm++) {
    #pragma unroll
    for (int tr = 0; tr < 4; tr++) {
      int r = tr * 16 + l15;
      float e0 = __expf(s[tm][tr][0] - mx[tr]);
      float e1 = __expf(s[tm][tr][1] - mx[tr]);
      float e2 = __expf(s[tm][tr][2] - mx[tr]);
      float e3 = __expf(s[tm][tr][3] - mx[tr]);
      sm[tr] += (e0 + e1) + (e2 + e3);
      uint2 pk;
      pk.x = pk2(e0, e1);
      pk.y = pk2(e2, e3);
      *(uint2*)&lp[r * 72 + tm * 16 + quad * 4] = pk;
    }
  }
  #pragma unroll
  for (int tr = 0; tr < 4; tr++) {
    sm[tr] += __shfl_xor(sm[tr], 16);
    sm[tr] += __shfl_xor(sm[tr], 32);
  }
  if (quad == 0) {
    #pragma unroll
    for (int tr = 0; tr < 4; tr++) rsum[tr * 16 + l15] = __builtin_amdgcn_rcpf(sm[tr]);
  }

  f32x4 o[4][2] = {};
  #pragma unroll
  for (int ks = 0; ks < 2; ks++) {
    bf16x8 vb0 = *(const bf16x8*)&lvt[(l15) * 72 + ks * 32 + quad * 8];
    bf16x8 vb1 = *(const bf16x8*)&lvt[(16 + l15) * 72 + ks * 32 + quad * 8];
    #pragma unroll
    for (int rt = 0; rt < 4; rt++) {
      bf16x8 pf = *(const bf16x8*)&lp[(rt * 16 + l15) * 72 + ks * 32 + quad * 8];
      o[rt][0] = __builtin_amdgcn_mfma_f32_16x16x32_bf16(pf, vb0, o[rt][0], 0, 0, 0);
      o[rt][1] = __builtin_amdgcn_mfma_f32_16x16x32_bf16(pf, vb1, o[rt][1], 0, 0, 0);
    }
  }
  #pragma unroll
  for (int rt = 0; rt < 4; rt++) {
    #pragma unroll
    for (int j = 0; j < 4; j++) {
      int r = rt * 16 + quad * 4 + j;
      if (r < 49) {
        float inv = rsum[r];
        int i = r / 7, jj = r - i * 7;
        int y = wy * 7 + i + 3;   if (y >= 56) y -= 56;
        int xx = wx * 7 + jj + 3; if (xx >= 56) xx -= 56;
        long base = ((long)(b * 3136 + y * 56 + xx)) * 192 + head * 32 + 2 * l15;
        *(unsigned int*)&attn[base] = pk2(o[rt][0][j] * inv, o[rt][1][j] * inv);
      }
    }
  }
}

extern "C" void kernel_launch(void* const* d_in, const int* in_sizes, int n_in,
                              void* d_out, int out_size, void* d_ws, size_t ws_size,
                              hipStream_t stream) {
  (void)in_sizes; (void)n_in; (void)out_size; (void)ws_size;
  const float* x      = (const float*)d_in[0];
  const float* ln1_g  = (const float*)d_in[3];
  const float* ln1_b  = (const float*)d_in[4];
  const float* qkv_w  = (const float*)d_in[5];
  const float* qkv_b  = (const float*)d_in[6];
  const float* rpb    = (const float*)d_in[7];
  const float* proj_w = (const float*)d_in[8];
  const float* proj_b = (const float*)d_in[9];
  const float* ln2_g  = (const float*)d_in[10];
  const float* ln2_b  = (const float*)d_in[11];
  const float* fc1_w  = (const float*)d_in[12];
  const float* fc1_b  = (const float*)d_in[13];
  const float* fc2_w  = (const float*)d_in[14];
  const float* fc2_b  = (const float*)d_in[15];

  // workspace layout (bytes), M=50176:
  //   [0,            38,535,168)  x2 fp32
  //   [38,535,168,   57,802,752)  hA bf16 (ln1 out / ln2 out; btab overlays)
  //   [57,802,752,  115,605,504)  qkv bf16
  //   [115,605,504, 134,873,088)  attn bf16
  //   [173,408,256, 174,587,904)  bf16 weights
  char* ws = (char*)d_ws;
  float* x2   = (float*)(ws + 0);
  u16* hA     = (u16*)(ws + 38535168);
  float* btab = (float*)(ws + 38535168);   // live only qkv->attn
  u16* qkv    = (u16*)(ws + 57802752);
  u16* attn   = (u16*)(ws + 115605504);
  u16* wbuf   = (u16*)(ws + 173408256);
  u16* qkv_wb  = wbuf;
  u16* proj_wb = wbuf + 110592;
  u16* fc1_wb  = wbuf + 147456;
  u16* fc2_wb  = wbuf + 368640;

  cast_weights<<<dim3(864), 256, 0, stream>>>(qkv_w, proj_w, fc1_w, fc2_w,
                                              qkv_wb, proj_wb, fc1_wb, fc2_wb);
  ln_kernel<<<dim3(12544), 256, 0, stream>>>(x, ln1_g, ln1_b, hA);
  gemm_kernel<0><<<dim3(392, 6), 256, 0, stream>>>(hA, qkv_wb, qkv_b, nullptr,
                                                   qkv, 576, 192);
  build_btab<<<dim3(96), 256, 0, stream>>>(rpb, btab);
  attn_kernel<<<dim3(1536), 256, 0, stream>>>(qkv, btab, attn);
  gemm_kernel<2><<<dim3(392, 2), 256, 0, stream>>>(attn, proj_wb, proj_b, x,
                                                   x2, 192, 192);
  ln_kernel<<<dim3(12544), 256, 0, stream>>>(x2, ln2_g, ln2_b, hA);
  mlp_kernel<<<dim3(784), 128, 0, stream>>>(hA, fc1_wb, fc1_b, fc2_wb, fc2_b,
                                            x2, (float*)d_out);
}

// Round 7
// 422.788 us; speedup vs baseline: 1.0054x; 1.0054x over previous
//
#include <hip/hip_runtime.h>

typedef unsigned short u16;
typedef __bf16 bf16x8 __attribute__((ext_vector_type(8)));
typedef __bf16 bf16x2_t __attribute__((ext_vector_type(2)));
typedef float f32x4 __attribute__((ext_vector_type(4)));

#define AS1 __attribute__((address_space(1)))
#define AS3 __attribute__((address_space(3)))

__device__ __forceinline__ void gld16(const void* g, void* l) {
  // 16B per lane: global per-lane gather -> LDS (wave-uniform base + lane*16)
  __builtin_amdgcn_global_load_lds((const AS1 void*)g, (AS3 void*)l, 16, 0, 0);
}

__device__ __forceinline__ u16 f2bf(float f) {
  union { float f; unsigned int u; } v; v.f = f;
  unsigned int u = v.u;
  u += 0x7fffu + ((u >> 16) & 1u);
  return (u16)(u >> 16);
}
__device__ __forceinline__ float bf2f(u16 h) {
  union { unsigned int u; float f; } v; v.u = ((unsigned int)h) << 16; return v.f;
}
// pack 2 fp32 -> 2 bf16 in one HW instr where available
__device__ __forceinline__ unsigned int pk2(float a, float b) {
#if __has_builtin(__builtin_amdgcn_cvt_pk_bf16_f32)
  union { bf16x2_t v; unsigned int u; } c;
  c.v = __builtin_amdgcn_cvt_pk_bf16_f32(a, b);
  return c.u;
#else
  return (unsigned int)f2bf(a) | ((unsigned int)f2bf(b) << 16);
#endif
}
// fast GELU: v * sigmoid(v*(1.5957691 + 0.0713548*v^2)); raw v_rcp (1 instr)
__device__ __forceinline__ float gelu_f(float v) {
  float u = v * (1.5957691216f + 0.0713548163f * v * v);
  return v * __builtin_amdgcn_rcpf(1.0f + __expf(-u));
}

// ---------------- cast weights fp32 -> bf16 ----------------
// proj_w gets head-interleaved column permutation to match attn's packed stores:
// attn lane holds (d, d+16) pairs -> stored at cols (2d, 2d+1) within the head.
__global__ __launch_bounds__(256) void cast_weights(
    const float* __restrict__ w0, const float* __restrict__ w1,
    const float* __restrict__ w2, const float* __restrict__ w3,
    u16* __restrict__ o0, u16* __restrict__ o1,
    u16* __restrict__ o2, u16* __restrict__ o3) {
  int i = blockIdx.x * 256 + threadIdx.x;
  if (i < 110592) o0[i] = f2bf(w0[i]);   // qkv_w 576x192
  if (i < 36864) {                        // proj_w 192x192, k-permuted
    int n = i / 192, kp = i - n * 192;
    int h = kp >> 5, dp = kp & 31;
    int d = (dp & 1) ? ((dp >> 1) + 16) : (dp >> 1);
    o1[i] = f2bf(w1[n * 192 + h * 32 + d]);
  }
  if (i < 221184) o2[i] = f2bf(w2[i]);   // fc1_w 1152x192
  if (i < 221184) o3[i] = f2bf(w3[i]);   // fc2_w 192x1152
}

// ---------------- bias table [6][64(key m)][64(query r)]; key>=49 -> -1e30 ----
__global__ __launch_bounds__(256) void build_btab(
    const float* __restrict__ rpb, float* __restrict__ btab) {
  int id = blockIdx.x * 256 + threadIdx.x;   // 96*256 = 24576
  int head = id >> 12;
  int m = (id >> 6) & 63;
  int r = id & 63;
  float v;
  if (m >= 49) v = -1e30f;                   // key mask folds into bias
  else if (r >= 49) v = 0.0f;
  else {
    int mi = m / 7, mj = m - mi * 7;
    int ri = r / 7, rj = r - ri * 7;
    v = rpb[((ri - mi + 6) * 13 + (rj - mj + 6)) * 6 + head];
  }
  btab[id] = v;
}

// ---------------- layernorm (fp32 in, bf16 out), 1 wave per row of 192 ----------------
__global__ __launch_bounds__(256) void ln_kernel(
    const float* __restrict__ x, const float* __restrict__ g,
    const float* __restrict__ b, u16* __restrict__ out) {
  int row = blockIdx.x * 4 + (threadIdx.x >> 6);
  int lane = threadIdx.x & 63;
  const float* xr = x + (long)row * 192;
  float e0 = xr[lane], e1 = xr[lane + 64], e2 = xr[lane + 128];
  float s = e0 + e1 + e2;
  #pragma unroll
  for (int o = 1; o < 64; o <<= 1) s += __shfl_xor(s, o);
  float mean = s * (1.0f / 192.0f);
  float d0 = e0 - mean, d1 = e1 - mean, d2 = e2 - mean;
  float q = d0 * d0 + d1 * d1 + d2 * d2;
  #pragma unroll
  for (int o = 1; o < 64; o <<= 1) q += __shfl_xor(q, o);
  float rstd = rsqrtf(q * (1.0f / 192.0f) + 1e-5f);
  u16* orow = out + (long)row * 192;
  orow[lane]       = f2bf(d0 * rstd * g[lane]       + b[lane]);
  orow[lane + 64]  = f2bf(d1 * rstd * g[lane + 64]  + b[lane + 64]);
  orow[lane + 128] = f2bf(d2 * rstd * g[lane + 128] + b[lane + 128]);
}

// ---------------- MFMA GEMM (qkv / proj): out[M,N] = A[M,K] @ W[N,K]^T + bias --
// Block tile 128x96, 4 waves 2x2 (wave tile 64x48), 16x16x32 bf16 MFMA.
// K chunked by 96, staged fragment-ordered via global_load_lds width-16.
// MODE 0: store bf16. MODE 2: +resid(fp32) -> fp32.
template<int MODE>
__global__ __launch_bounds__(256, 3) void gemm_kernel(
    const u16* __restrict__ A, const u16* __restrict__ W,
    const float* __restrict__ bias, const float* __restrict__ resid,
    void* __restrict__ out, int N, int K) {
  __shared__ u16 lds[25600];           // 51,200 B (epilogue 128x100 f32 overlay)
  float* ct = (float*)lds;
  const int tid = threadIdx.x;
  const int wave = tid >> 6, lane = tid & 63;
  const int wm = wave >> 1, wn = wave & 1;
  const int quad = lane >> 4, l15 = lane & 15;
  const long bm = (long)blockIdx.x * 128;
  const int bn = blockIdx.y * 96;

  f32x4 acc[4][3] = {};
  for (int kc = 0; kc < K; kc += 96) {
    if (kc) __syncthreads();           // LDS reuse across chunks
    for (int t = wave; t < 42; t += 4) {
      int isB = t >= 24;
      int tt = isB ? t - 24 : t;
      int grp = tt / 3, kt = tt - grp * 3;
      const u16* g = isB
          ? (W + (long)(bn + grp * 16 + l15) * K + kc + kt * 32 + quad * 8)
          : (A + (bm + grp * 16 + l15) * K + kc + kt * 32 + quad * 8);
      gld16(g, &lds[(isB ? 12288 : 0) + tt * 512]);
    }
    __syncthreads();
    #pragma unroll
    for (int kt = 0; kt < 3; kt++) {
      bf16x8 af[4], bfr[3];
      #pragma unroll
      for (int mt = 0; mt < 4; mt++)
        af[mt] = *(const bf16x8*)&lds[((wm * 4 + mt) * 3 + kt) * 512 + lane * 8];
      #pragma unroll
      for (int nt = 0; nt < 3; nt++)
        bfr[nt] = *(const bf16x8*)&lds[12288 + ((wn * 3 + nt) * 3 + kt) * 512 + lane * 8];
      #pragma unroll
      for (int mt = 0; mt < 4; mt++)
        #pragma unroll
        for (int nt = 0; nt < 3; nt++)
          acc[mt][nt] = __builtin_amdgcn_mfma_f32_16x16x32_bf16(af[mt], bfr[nt], acc[mt][nt], 0, 0, 0);
    }
  }
  __syncthreads();
  // ---- epilogue: acc(+bias) -> LDS fp32 [128][100] ----
  #pragma unroll
  for (int nt = 0; nt < 3; nt++) {
    int col = wn * 48 + nt * 16 + l15;
    float bi = bias[bn + col];
    #pragma unroll
    for (int mt = 0; mt < 4; mt++) {
      int row0 = wm * 64 + mt * 16 + quad * 4;
      #pragma unroll
      for (int j = 0; j < 4; j++)
        ct[(row0 + j) * 100 + col] = acc[mt][nt][j] + bi;
    }
  }
  __syncthreads();
  // ---- coalesced writeout: 3072 float4 chunks (128 rows x 24 groups) ----
  #pragma unroll
  for (int it = 0; it < 12; it++) {
    int c = it * 256 + tid;
    int row = c / 24, i = c - row * 24;
    float4 v = *(const float4*)&ct[row * 100 + i * 4];
    long idx = (bm + row) * (long)N + bn + i * 4;
    if (MODE == 2) {
      const float4 rv = *(const float4*)(resid + idx);
      v.x += rv.x; v.y += rv.y; v.z += rv.z; v.w += rv.w;
      *(float4*)((float*)out + idx) = v;
    } else {
      uint2 pk;
      pk.x = pk2(v.x, v.y);
      pk.y = pk2(v.z, v.w);
      *(uint2*)((u16*)out + idx) = pk;
    }
  }
}

// ---------------- fused MLP v3: out = x2 + gelu(hA@W1^T+b1) @ W2^T + b2 -------
// 2 waves/block, 32 rows/wave (grid 784). hA staged ONCE into LDS frag-order
// (wave-private tiles; one barrier for the vmcnt drain). Hidden processed in
// 12 chunks of 96. Per chunk: fc1-T MFMA (W1-frags BATCH-loaded 6-wide into
// registers -> 6+ outstanding vmem ops), GELU+pack -> wave-private LDS in
// fc2-A-frag order, fc2 accumulate (W2-frags batch-loaded 12-wide).
// No intermediate HBM traffic; W1/W2 reads are L2-broadcast.
__global__ __launch_bounds__(128, 2) void mlp_kernel(
    const u16* __restrict__ hA, const u16* __restrict__ W1,
    const float* __restrict__ b1, const u16* __restrict__ W2,
    const float* __restrict__ b2, const float* __restrict__ x2,
    float* __restrict__ out) {
  // LDS: [0,12288) hA 24 tiles of 512 u16 (tile = (wave*2+rt)*6+kt);
  //      [12288,18432) per-wave hid chunk (6 tiles of 512 u16 each wave)
  __shared__ u16 lds[18432];           // 36,864 B -> 4 blocks/CU capacity
  const int tid = threadIdx.x;
  const int wave = tid >> 6, lane = tid & 63;
  const int quad = lane >> 4, l15 = lane & 15;
  u16* hx = lds + 12288 + wave * 3072;
  const long R = ((long)blockIdx.x * 2 + wave) * 32;

  // ---- stage this wave's 32 rows of hA (12 tiles), fragment-ordered ----
  #pragma unroll
  for (int rt = 0; rt < 2; rt++)
    #pragma unroll
    for (int kt = 0; kt < 6; kt++)
      gld16(hA + (R + rt * 16 + l15) * 192 + kt * 32 + quad * 8,
            &lds[((wave * 2 + rt) * 6 + kt) * 512]);
  __syncthreads();   // drain global_load_lds before ds_read

  f32x4 acc2[2][12] = {};
  for (int nc = 0; nc < 12; nc++) {
    // ---- phase 1: hidT[c][r] = W1chunk @ hA^T (W1 frags batched per kt) ----
    f32x4 acc1[6][2] = {};
    #pragma unroll
    for (int kt = 0; kt < 6; kt++) {
      bf16x8 w1f[6];
      #pragma unroll
      for (int c = 0; c < 6; c++)
        w1f[c] = *(const bf16x8*)(W1 + (long)(nc * 96 + c * 16 + l15) * 192 + kt * 32 + quad * 8);
      bf16x8 a0 = *(const bf16x8*)&lds[((wave * 2 + 0) * 6 + kt) * 512 + lane * 8];
      bf16x8 a1 = *(const bf16x8*)&lds[((wave * 2 + 1) * 6 + kt) * 512 + lane * 8];
      #pragma unroll
      for (int c = 0; c < 6; c++) {
        acc1[c][0] = __builtin_amdgcn_mfma_f32_16x16x32_bf16(w1f[c], a0, acc1[c][0], 0, 0, 0);
        acc1[c][1] = __builtin_amdgcn_mfma_f32_16x16x32_bf16(w1f[c], a1, acc1[c][1], 0, 0, 0);
      }
    }
    // ---- phase 2: bias1 + gelu + pack -> LDS in fc2-A-fragment order ----
    // lane holds c = ctt*16 + quad*4 + j (j=0..3), row r = rt*16 + l15.
    #pragma unroll
    for (int ctt = 0; ctt < 6; ctt++) {
      float4 bb = *(const float4*)(b1 + nc * 96 + ctt * 16 + quad * 4);
      #pragma unroll
      for (int rt = 0; rt < 2; rt++) {
        float g0 = gelu_f(acc1[ctt][rt][0] + bb.x);
        float g1 = gelu_f(acc1[ctt][rt][1] + bb.y);
        float g2 = gelu_f(acc1[ctt][rt][2] + bb.z);
        float g3 = gelu_f(acc1[ctt][rt][3] + bb.w);
        uint2 pk;
        pk.x = pk2(g0, g1);
        pk.y = pk2(g2, g3);
        int addr = (rt * 3 + (ctt >> 1)) * 512 + ((ctt & 1) * 2 + (quad >> 1)) * 128
                 + l15 * 8 + (quad & 1) * 4;
        *(uint2*)&hx[addr] = pk;
      }
    }
    // ---- phase 3: fc2 accumulate (W2 frags batched per kt2) ----
    #pragma unroll
    for (int kt2 = 0; kt2 < 3; kt2++) {
      bf16x8 w2f[12];
      #pragma unroll
      for (int nt = 0; nt < 12; nt++)
        w2f[nt] = *(const bf16x8*)(W2 + (long)(nt * 16 + l15) * 1152 + nc * 96 + kt2 * 32 + quad * 8);
      bf16x8 h0 = *(const bf16x8*)&hx[kt2 * 512 + lane * 8];
      bf16x8 h1 = *(const bf16x8*)&hx[(3 + kt2) * 512 + lane * 8];
      #pragma unroll
      for (int nt = 0; nt < 12; nt++) {
        acc2[0][nt] = __builtin_amdgcn_mfma_f32_16x16x32_bf16(w2f[nt], h0, acc2[0][nt], 0, 0, 0);
        acc2[1][nt] = __builtin_amdgcn_mfma_f32_16x16x32_bf16(w2f[nt], h1, acc2[1][nt], 0, 0, 0);
      }
    }
  }
  // ---- epilogue: lane holds out col = nt*16 + quad*4 + j, row = rt*16 + l15 ----
  #pragma unroll
  for (int nt = 0; nt < 12; nt++) {
    float4 bb = *(const float4*)(b2 + nt * 16 + quad * 4);
    #pragma unroll
    for (int rt = 0; rt < 2; rt++) {
      long idx = (R + rt * 16 + l15) * 192 + nt * 16 + quad * 4;
      float4 rv = *(const float4*)(x2 + idx);
      float4 v;
      v.x = acc2[rt][nt][0] + bb.x + rv.x;
      v.y = acc2[rt][nt][1] + bb.y + rv.y;
      v.z = acc2[rt][nt][2] + bb.z + rv.z;
      v.w = acc2[rt][nt][3] + bb.w + rv.w;
      *(float4*)(out + idx) = v;
    }
  }
}

// ---------------- MFMA windowed attention: 1 wave per (window, head) ----------------
__global__ __launch_bounds__(256) void attn_kernel(
    const u16* __restrict__ qkv, const float* __restrict__ btab,
    u16* __restrict__ attn) {
  // per-wave u16: P 64x72 = 4608 | Vt 32x72 = 2304 | rsum 64 f32 = 128
  __shared__ u16 lds[4 * 7040];   // 56,320 B
  int tid = threadIdx.x;
  int wave = tid >> 6, lane = tid & 63;
  int quad = lane >> 4, l15 = lane & 15;
  int w = blockIdx.x * 4 + wave;
  int win = w / 6, head = w - win * 6;
  int b = win >> 6, wy = (win >> 3) & 7, wx = win & 7;
  u16* lp = lds + wave * 7040;
  u16* lvt = lp + 4608;
  float* rsum = (float*)(lp + 6912);

  bf16x8 qb[4], ka[4];
  #pragma unroll
  for (int t = 0; t < 4; t++) {
    int n = t * 16 + l15;
    uint4 qv = {0, 0, 0, 0}, kv = {0, 0, 0, 0}, vv = {0, 0, 0, 0};
    if (n < 49) {
      int i = n / 7, j = n - i * 7;
      int y = wy * 7 + i + 3;  if (y >= 56) y -= 56;
      int xx = wx * 7 + j + 3; if (xx >= 56) xx -= 56;
      long base = ((long)(b * 3136 + y * 56 + xx)) * 576 + head * 32 + quad * 8;
      qv = *(const uint4*)(qkv + base);
      kv = *(const uint4*)(qkv + base + 192);
      vv = *(const uint4*)(qkv + base + 384);
    }
    qb[t] = *(const bf16x8*)&qv;
    ka[t] = *(const bf16x8*)&kv;
    const u16* vp = (const u16*)&vv;
    #pragma unroll
    for (int d = 0; d < 8; d++) lvt[(quad * 8 + d) * 72 + n] = vp[d];
  }

  f32x4 s[4][4];
  const f32x4 fz = {0.0f, 0.0f, 0.0f, 0.0f};
  #pragma unroll
  for (int tm = 0; tm < 4; tm++)
    #pragma unroll
    for (int tr = 0; tr < 4; tr++)
      s[tm][tr] = __builtin_amdgcn_mfma_f32_16x16x32_bf16(ka[tm], qb[tr], fz, 0, 0, 0);

  const float scale = 0.17677669529663687f;  // 32^-0.5
  const float* bt = btab + head * 4096;
  float mx[4] = {-1e30f, -1e30f, -1e30f, -1e30f};
  #pragma unroll
  for (int tm = 0; tm < 4; tm++) {
    int m0 = tm * 16 + quad * 4;
    #pragma unroll
    for (int tr = 0; tr < 4; tr++) {
      int r = tr * 16 + l15;
      #pragma unroll
      for (int j = 0; j < 4; j++) {
        float v = s[tm][tr][j] * scale + bt[(m0 + j) * 64 + r];
        s[tm][tr][j] = v;
        mx[tr] = fmaxf(mx[tr], v);
      }
    }
  }
  #pragma unroll
  for (int tr = 0; tr < 4; tr++) {
    mx[tr] = fmaxf(mx[tr], __shfl_xor(mx[tr], 16));
    mx[tr] = fmaxf(mx[tr], __shfl_xor(mx[tr], 32));
  }
  float sm[4] = {0.f, 0.f, 0.f, 0.f};
  #pragma unroll
  for (int tm = 0; tm < 4; tm++) {
    #pragma unroll
    for (int tr = 0; tr < 4; tr++) {
      int r = tr * 16 + l15;
      float e0 = __expf(s[tm][tr][0] - mx[tr]);
      float e1 = __expf(s[tm][tr][1] - mx[tr]);
      float e2 = __expf(s[tm][tr][2] - mx[tr]);
      float e3 = __expf(s[tm][tr][3] - mx[tr]);
      sm[tr] += (e0 + e1) + (e2 + e3);
      uint2 pk;
      pk.x = pk2(e0, e1);
      pk.y = pk2(e2, e3);
      *(uint2*)&lp[r * 72 + tm * 16 + quad * 4] = pk;
    }
  }
  #pragma unroll
  for (int tr = 0; tr < 4; tr++) {
    sm[tr] += __shfl_xor(sm[tr], 16);
    sm[tr] += __shfl_xor(sm[tr], 32);
  }
  if (quad == 0) {
    #pragma unroll
    for (int tr = 0; tr < 4; tr++) rsum[tr * 16 + l15] = __builtin_amdgcn_rcpf(sm[tr]);
  }

  f32x4 o[4][2] = {};
  #pragma unroll
  for (int ks = 0; ks < 2; ks++) {
    bf16x8 vb0 = *(const bf16x8*)&lvt[(l15) * 72 + ks * 32 + quad * 8];
    bf16x8 vb1 = *(const bf16x8*)&lvt[(16 + l15) * 72 + ks * 32 + quad * 8];
    #pragma unroll
    for (int rt = 0; rt < 4; rt++) {
      bf16x8 pf = *(const bf16x8*)&lp[(rt * 16 + l15) * 72 + ks * 32 + quad * 8];
      o[rt][0] = __builtin_amdgcn_mfma_f32_16x16x32_bf16(pf, vb0, o[rt][0], 0, 0, 0);
      o[rt][1] = __builtin_amdgcn_mfma_f32_16x16x32_bf16(pf, vb1, o[rt][1], 0, 0, 0);
    }
  }
  #pragma unroll
  for (int rt = 0; rt < 4; rt++) {
    #pragma unroll
    for (int j = 0; j < 4; j++) {
      int r = rt * 16 + quad * 4 + j;
      if (r < 49) {
        float inv = rsum[r];
        int i = r / 7, jj = r - i * 7;
        int y = wy * 7 + i + 3;   if (y >= 56) y -= 56;
        int xx = wx * 7 + jj + 3; if (xx >= 56) xx -= 56;
        long base = ((long)(b * 3136 + y * 56 + xx)) * 192 + head * 32 + 2 * l15;
        *(unsigned int*)&attn[base] = pk2(o[rt][0][j] * inv, o[rt][1][j] * inv);
      }
    }
  }
}

extern "C" void kernel_launch(void* const* d_in, const int* in_sizes, int n_in,
                              void* d_out, int out_size, void* d_ws, size_t ws_size,
                              hipStream_t stream) {
  (void)in_sizes; (void)n_in; (void)out_size; (void)ws_size;
  const float* x      = (const float*)d_in[0];
  const float* ln1_g  = (const float*)d_in[3];
  const float* ln1_b  = (const float*)d_in[4];
  const float* qkv_w  = (const float*)d_in[5];
  const float* qkv_b  = (const float*)d_in[6];
  const float* rpb    = (const float*)d_in[7];
  const float* proj_w = (const float*)d_in[8];
  const float* proj_b = (const float*)d_in[9];
  const float* ln2_g  = (const float*)d_in[10];
  const float* ln2_b  = (const float*)d_in[11];
  const float* fc1_w  = (const float*)d_in[12];
  const float* fc1_b  = (const float*)d_in[13];
  const float* fc2_w  = (const float*)d_in[14];
  const float* fc2_b  = (const float*)d_in[15];

  // workspace layout (bytes), M=50176:
  //   [0,            38,535,168)  x2 fp32
  //   [38,535,168,   57,802,752)  hA bf16 (ln1 out / ln2 out; btab overlays)
  //   [57,802,752,  115,605,504)  qkv bf16
  //   [115,605,504, 134,873,088)  attn bf16
  //   [173,408,256, 174,587,904)  bf16 weights
  char* ws = (char*)d_ws;
  float* x2   = (float*)(ws + 0);
  u16* hA     = (u16*)(ws + 38535168);
  float* btab = (float*)(ws + 38535168);   // live only qkv->attn
  u16* qkv    = (u16*)(ws + 57802752);
  u16* attn   = (u16*)(ws + 115605504);
  u16* wbuf   = (u16*)(ws + 173408256);
  u16* qkv_wb  = wbuf;
  u16* proj_wb = wbuf + 110592;
  u16* fc1_wb  = wbuf + 147456;
  u16* fc2_wb  = wbuf + 368640;

  cast_weights<<<dim3(864), 256, 0, stream>>>(qkv_w, proj_w, fc1_w, fc2_w,
                                              qkv_wb, proj_wb, fc1_wb, fc2_wb);
  ln_kernel<<<dim3(12544), 256, 0, stream>>>(x, ln1_g, ln1_b, hA);
  gemm_kernel<0><<<dim3(392, 6), 256, 0, stream>>>(hA, qkv_wb, qkv_b, nullptr,
                                                   qkv, 576, 192);
  build_btab<<<dim3(96), 256, 0, stream>>>(rpb, btab);
  attn_kernel<<<dim3(1536), 256, 0, stream>>>(qkv, btab, attn);
  gemm_kernel<2><<<dim3(392, 2), 256, 0, stream>>>(attn, proj_wb, proj_b, x,
                                                   x2, 192, 192);
  ln_kernel<<<dim3(12544), 256, 0, stream>>>(x2, ln2_g, ln2_b, hA);
  mlp_kernel<<<dim3(784), 128, 0, stream>>>(hA, fc1_wb, fc1_b, fc2_wb, fc2_b,
                                            x2, (float*)d_out);
}

// Round 8
// 341.911 us; speedup vs baseline: 1.2433x; 1.2365x over previous
//
#include <hip/hip_runtime.h>

typedef unsigned short u16;
typedef __bf16 bf16x8 __attribute__((ext_vector_type(8)));
typedef __bf16 bf16x2_t __attribute__((ext_vector_type(2)));
typedef float f32x4 __attribute__((ext_vector_type(4)));

#define AS1 __attribute__((address_space(1)))
#define AS3 __attribute__((address_space(3)))

__device__ __forceinline__ void gld16(const void* g, void* l) {
  // 16B per lane: global per-lane gather -> LDS (wave-uniform base + lane*16)
  __builtin_amdgcn_global_load_lds((const AS1 void*)g, (AS3 void*)l, 16, 0, 0);
}

__device__ __forceinline__ u16 f2bf(float f) {
  union { float f; unsigned int u; } v; v.f = f;
  unsigned int u = v.u;
  u += 0x7fffu + ((u >> 16) & 1u);
  return (u16)(u >> 16);
}
__device__ __forceinline__ float bf2f(u16 h) {
  union { unsigned int u; float f; } v; v.u = ((unsigned int)h) << 16; return v.f;
}
// pack 2 fp32 -> 2 bf16 in one HW instr where available
__device__ __forceinline__ unsigned int pk2(float a, float b) {
#if __has_builtin(__builtin_amdgcn_cvt_pk_bf16_f32)
  union { bf16x2_t v; unsigned int u; } c;
  c.v = __builtin_amdgcn_cvt_pk_bf16_f32(a, b);
  return c.u;
#else
  return (unsigned int)f2bf(a) | ((unsigned int)f2bf(b) << 16);
#endif
}
// fast GELU: v * sigmoid(v*(1.5957691 + 0.0713548*v^2)); raw v_rcp (1 instr)
__device__ __forceinline__ float gelu_f(float v) {
  float u = v * (1.5957691216f + 0.0713548163f * v * v);
  return v * __builtin_amdgcn_rcpf(1.0f + __expf(-u));
}

// ---------------- cast weights fp32 -> bf16 ----------------
// proj_w gets head-interleaved column permutation to match attn's packed stores:
// attn lane holds (d, d+16) pairs -> stored at cols (2d, 2d+1) within the head.
__global__ __launch_bounds__(256) void cast_weights(
    const float* __restrict__ w0, const float* __restrict__ w1,
    const float* __restrict__ w2, const float* __restrict__ w3,
    u16* __restrict__ o0, u16* __restrict__ o1,
    u16* __restrict__ o2, u16* __restrict__ o3) {
  int i = blockIdx.x * 256 + threadIdx.x;
  if (i < 110592) o0[i] = f2bf(w0[i]);   // qkv_w 576x192
  if (i < 36864) {                        // proj_w 192x192, k-permuted
    int n = i / 192, kp = i - n * 192;
    int h = kp >> 5, dp = kp & 31;
    int d = (dp & 1) ? ((dp >> 1) + 16) : (dp >> 1);
    o1[i] = f2bf(w1[n * 192 + h * 32 + d]);
  }
  if (i < 221184) o2[i] = f2bf(w2[i]);   // fc1_w 1152x192
  if (i < 221184) o3[i] = f2bf(w3[i]);   // fc2_w 192x1152
}

// ---------------- bias table [6][64(key m)][64(query r)]; key>=49 -> -1e30 ----
__global__ __launch_bounds__(256) void build_btab(
    const float* __restrict__ rpb, float* __restrict__ btab) {
  int id = blockIdx.x * 256 + threadIdx.x;   // 96*256 = 24576
  int head = id >> 12;
  int m = (id >> 6) & 63;
  int r = id & 63;
  float v;
  if (m >= 49) v = -1e30f;                   // key mask folds into bias
  else if (r >= 49) v = 0.0f;
  else {
    int mi = m / 7, mj = m - mi * 7;
    int ri = r / 7, rj = r - ri * 7;
    v = rpb[((ri - mi + 6) * 13 + (rj - mj + 6)) * 6 + head];
  }
  btab[id] = v;
}

// ---------------- layernorm (fp32 in, bf16 out), 1 wave per row of 192 ----------------
__global__ __launch_bounds__(256) void ln_kernel(
    const float* __restrict__ x, const float* __restrict__ g,
    const float* __restrict__ b, u16* __restrict__ out) {
  int row = blockIdx.x * 4 + (threadIdx.x >> 6);
  int lane = threadIdx.x & 63;
  const float* xr = x + (long)row * 192;
  float e0 = xr[lane], e1 = xr[lane + 64], e2 = xr[lane + 128];
  float s = e0 + e1 + e2;
  #pragma unroll
  for (int o = 1; o < 64; o <<= 1) s += __shfl_xor(s, o);
  float mean = s * (1.0f / 192.0f);
  float d0 = e0 - mean, d1 = e1 - mean, d2 = e2 - mean;
  float q = d0 * d0 + d1 * d1 + d2 * d2;
  #pragma unroll
  for (int o = 1; o < 64; o <<= 1) q += __shfl_xor(q, o);
  float rstd = rsqrtf(q * (1.0f / 192.0f) + 1e-5f);
  u16* orow = out + (long)row * 192;
  orow[lane]       = f2bf(d0 * rstd * g[lane]       + b[lane]);
  orow[lane + 64]  = f2bf(d1 * rstd * g[lane + 64]  + b[lane + 64]);
  orow[lane + 128] = f2bf(d2 * rstd * g[lane + 128] + b[lane + 128]);
}

// ---------------- MFMA GEMM: out[M,N] = A[M,K] @ W[N,K]^T + bias ----------------
// Block tile 128x96, 4 waves 2x2 (wave tile 64x48), 16x16x32 bf16 MFMA.
// DOUBLE-BUFFERED K-loop, chunk = 32: stage chunk c+1 into the alternate LDS
// buffer BEFORE computing chunk c; single barrier per chunk. The compiler's
// vmcnt(0) drain before s_barrier then lands AFTER the MFMAs, so the
// global_load_lds of chunk c+1 overlaps compute of chunk c. Staging is
// fragment-ordered (conflict-free ds_read_b128 at lane*8 u16).
// LDS = 2 x 14 tiles x 1KB = 28,672 B -> 5 blocks/CU LDS-side.
// Epilogue: two 64-row passes through the staging LDS (64x100 fp32) ->
// fully-coalesced line stores.
// MODE 0: store bf16. MODE 1: fast-GELU -> bf16. MODE 2: +resid(fp32) -> fp32.
// Requires K % 32 == 0, N % 96 == 0, M % 128 == 0.
template<int MODE>
__global__ __launch_bounds__(256, 4) void gemm_kernel(
    const u16* __restrict__ A, const u16* __restrict__ W,
    const float* __restrict__ bias, const float* __restrict__ resid,
    void* __restrict__ out, int N, int K) {
  // per buffer: A tiles 0..7 (rows g*16+l15), B tiles 8..13 (cols n*16+l15)
  __shared__ u16 lds[2 * 7168];        // 28,672 B
  float* ct = (float*)lds;             // epilogue overlay: 64 x 100 fp32 (25,600 B)
  const int tid = threadIdx.x;
  const int wave = tid >> 6, lane = tid & 63;
  const int wm = wave >> 1, wn = wave & 1;
  const int quad = lane >> 4, l15 = lane & 15;
  const long bm = (long)blockIdx.x * 128;
  const int bn = blockIdx.y * 96;
  const int NC = K >> 5;

  // ---- prologue: stage chunk 0 into buf 0 ----
  for (int t = wave; t < 14; t += 4) {
    const u16* g = (t < 8)
        ? (A + (bm + t * 16 + l15) * K + quad * 8)
        : (W + (long)(bn + (t - 8) * 16 + l15) * K + quad * 8);
    gld16(g, &lds[t * 512]);
  }
  __syncthreads();

  f32x4 acc[4][3] = {};
  for (int c = 0; c < NC; c++) {
    const int cur = c & 1;
    if (c + 1 < NC) {
      const int kof = (c + 1) * 32 + quad * 8;
      const int nb = (cur ^ 1) * 7168;
      for (int t = wave; t < 14; t += 4) {
        const u16* g = (t < 8)
            ? (A + (bm + t * 16 + l15) * K + kof)
            : (W + (long)(bn + (t - 8) * 16 + l15) * K + kof);
        gld16(g, &lds[nb + t * 512]);
      }
    }
    const u16* buf = lds + cur * 7168;
    bf16x8 af[4], bfr[3];
    #pragma unroll
    for (int mt = 0; mt < 4; mt++)
      af[mt] = *(const bf16x8*)&buf[(wm * 4 + mt) * 512 + lane * 8];
    #pragma unroll
    for (int nt = 0; nt < 3; nt++)
      bfr[nt] = *(const bf16x8*)&buf[(8 + wn * 3 + nt) * 512 + lane * 8];
    #pragma unroll
    for (int mt = 0; mt < 4; mt++)
      #pragma unroll
      for (int nt = 0; nt < 3; nt++)
        acc[mt][nt] = __builtin_amdgcn_mfma_f32_16x16x32_bf16(af[mt], bfr[nt], acc[mt][nt], 0, 0, 0);
    __syncthreads();   // drains chunk c+1 staging; guards buf reuse
  }

  // ---- epilogue: two 64-row passes (waves with wm==h own the rows) ----
  #pragma unroll
  for (int h = 0; h < 2; h++) {
    if (wm == h) {
      #pragma unroll
      for (int nt = 0; nt < 3; nt++) {
        int col = wn * 48 + nt * 16 + l15;
        float bi = bias[bn + col];
        #pragma unroll
        for (int mt = 0; mt < 4; mt++) {
          int row0 = mt * 16 + quad * 4;
          #pragma unroll
          for (int j = 0; j < 4; j++)
            ct[(row0 + j) * 100 + col] = acc[mt][nt][j] + bi;
        }
      }
    }
    __syncthreads();
    // 64 rows x 24 float4-groups = 1536 chunks, 6 per thread
    #pragma unroll
    for (int it = 0; it < 6; it++) {
      int cc = it * 256 + tid;
      int row = cc / 24, i = cc - row * 24;
      float4 v = *(const float4*)&ct[row * 100 + i * 4];
      long idx = (bm + h * 64 + row) * (long)N + bn + i * 4;
      if (MODE == 2) {
        const float4 rv = *(const float4*)(resid + idx);
        v.x += rv.x; v.y += rv.y; v.z += rv.z; v.w += rv.w;
        *(float4*)((float*)out + idx) = v;
      } else {
        if (MODE == 1) {
          v.x = gelu_f(v.x); v.y = gelu_f(v.y); v.z = gelu_f(v.z); v.w = gelu_f(v.w);
        }
        uint2 pk;
        pk.x = pk2(v.x, v.y);
        pk.y = pk2(v.z, v.w);
        *(uint2*)((u16*)out + idx) = pk;
      }
    }
    if (h == 0) __syncthreads();
  }
}

// ---------------- MFMA windowed attention: 1 wave per (window, head) ----------------
__global__ __launch_bounds__(256) void attn_kernel(
    const u16* __restrict__ qkv, const float* __restrict__ btab,
    u16* __restrict__ attn) {
  // per-wave u16: P 64x72 = 4608 | Vt 32x72 = 2304 | rsum 64 f32 = 128
  __shared__ u16 lds[4 * 7040];   // 56,320 B
  int tid = threadIdx.x;
  int wave = tid >> 6, lane = tid & 63;
  int quad = lane >> 4, l15 = lane & 15;
  int w = blockIdx.x * 4 + wave;
  int win = w / 6, head = w - win * 6;
  int b = win >> 6, wy = (win >> 3) & 7, wx = win & 7;
  u16* lp = lds + wave * 7040;
  u16* lvt = lp + 4608;
  float* rsum = (float*)(lp + 6912);

  bf16x8 qb[4], ka[4];
  #pragma unroll
  for (int t = 0; t < 4; t++) {
    int n = t * 16 + l15;
    uint4 qv = {0, 0, 0, 0}, kv = {0, 0, 0, 0}, vv = {0, 0, 0, 0};
    if (n < 49) {
      int i = n / 7, j = n - i * 7;
      int y = wy * 7 + i + 3;  if (y >= 56) y -= 56;
      int xx = wx * 7 + j + 3; if (xx >= 56) xx -= 56;
      long base = ((long)(b * 3136 + y * 56 + xx)) * 576 + head * 32 + quad * 8;
      qv = *(const uint4*)(qkv + base);
      kv = *(const uint4*)(qkv + base + 192);
      vv = *(const uint4*)(qkv + base + 384);
    }
    qb[t] = *(const bf16x8*)&qv;
    ka[t] = *(const bf16x8*)&kv;
    const u16* vp = (const u16*)&vv;
    #pragma unroll
    for (int d = 0; d < 8; d++) lvt[(quad * 8 + d) * 72 + n] = vp[d];
  }

  f32x4 s[4][4];
  const f32x4 fz = {0.0f, 0.0f, 0.0f, 0.0f};
  #pragma unroll
  for (int tm = 0; tm < 4; tm++)
    #pragma unroll
    for (int tr = 0; tr < 4; tr++)
      s[tm][tr] = __builtin_amdgcn_mfma_f32_16x16x32_bf16(ka[tm], qb[tr], fz, 0, 0, 0);

  const float scale = 0.17677669529663687f;  // 32^-0.5
  const float* bt = btab + head * 4096;
  float mx[4] = {-1e30f, -1e30f, -1e30f, -1e30f};
  #pragma unroll
  for (int tm = 0; tm < 4; tm++) {
    int m0 = tm * 16 + quad * 4;
    #pragma unroll
    for (int tr = 0; tr < 4; tr++) {
      int r = tr * 16 + l15;
      #pragma unroll
      for (int j = 0; j < 4; j++) {
        float v = s[tm][tr][j] * scale + bt[(m0 + j) * 64 + r];
        s[tm][tr][j] = v;
        mx[tr] = fmaxf(mx[tr], v);
      }
    }
  }
  #pragma unroll
  for (int tr = 0; tr < 4; tr++) {
    mx[tr] = fmaxf(mx[tr], __shfl_xor(mx[tr], 16));
    mx[tr] = fmaxf(mx[tr], __shfl_xor(mx[tr], 32));
  }
  float sm[4] = {0.f, 0.f, 0.f, 0.f};
  #pragma unroll
  for (int tm = 0; tm < 4; tm++) {
    #pragma unroll
    for (int tr = 0; tr < 4; tr++) {
      int r = tr * 16 + l15;
      float e0 = __expf(s[tm][tr][0] - mx[tr]);
      float e1 = __expf(s[tm][tr][1] - mx[tr]);
      float e2 = __expf(s[tm][tr][2] - mx[tr]);
      float e3 = __expf(s[tm][tr][3] - mx[tr]);
      sm[tr] += (e0 + e1) + (e2 + e3);
      uint2 pk;
      pk.x = pk2(e0, e1);
      pk.y = pk2(e2, e3);
      *(uint2*)&lp[r * 72 + tm * 16 + quad * 4] = pk;
    }
  }
  #pragma unroll
  for (int tr = 0; tr < 4; tr++) {
    sm[tr] += __shfl_xor(sm[tr], 16);
    sm[tr] += __shfl_xor(sm[tr], 32);
  }
  if (quad == 0) {
    #pragma unroll
    for (int tr = 0; tr < 4; tr++) rsum[tr * 16 + l15] = __builtin_amdgcn_rcpf(sm[tr]);
  }

  f32x4 o[4][2] = {};
  #pragma unroll
  for (int ks = 0; ks < 2; ks++) {
    bf16x8 vb0 = *(const bf16x8*)&lvt[(l15) * 72 + ks * 32 + quad * 8];
    bf16x8 vb1 = *(const bf16x8*)&lvt[(16 + l15) * 72 + ks * 32 + quad * 8];
    #pragma unroll
    for (int rt = 0; rt < 4; rt++) {
      bf16x8 pf = *(const bf16x8*)&lp[(rt * 16 + l15) * 72 + ks * 32 + quad * 8];
      o[rt][0] = __builtin_amdgcn_mfma_f32_16x16x32_bf16(pf, vb0, o[rt][0], 0, 0, 0);
      o[rt][1] = __builtin_amdgcn_mfma_f32_16x16x32_bf16(pf, vb1, o[rt][1], 0, 0, 0);
    }
  }
  #pragma unroll
  for (int rt = 0; rt < 4; rt++) {
    #pragma unroll
    for (int j = 0; j < 4; j++) {
      int r = rt * 16 + quad * 4 + j;
      if (r < 49) {
        float inv = rsum[r];
        int i = r / 7, jj = r - i * 7;
        int y = wy * 7 + i + 3;   if (y >= 56) y -= 56;
        int xx = wx * 7 + jj + 3; if (xx >= 56) xx -= 56;
        long base = ((long)(b * 3136 + y * 56 + xx)) * 192 + head * 32 + 2 * l15;
        *(unsigned int*)&attn[base] = pk2(o[rt][0][j] * inv, o[rt][1][j] * inv);
      }
    }
  }
}

extern "C" void kernel_launch(void* const* d_in, const int* in_sizes, int n_in,
                              void* d_out, int out_size, void* d_ws, size_t ws_size,
                              hipStream_t stream) {
  (void)in_sizes; (void)n_in; (void)out_size; (void)ws_size;
  const float* x      = (const float*)d_in[0];
  const float* ln1_g  = (const float*)d_in[3];
  const float* ln1_b  = (const float*)d_in[4];
  const float* qkv_w  = (const float*)d_in[5];
  const float* qkv_b  = (const float*)d_in[6];
  const float* rpb    = (const float*)d_in[7];
  const float* proj_w = (const float*)d_in[8];
  const float* proj_b = (const float*)d_in[9];
  const float* ln2_g  = (const float*)d_in[10];
  const float* ln2_b  = (const float*)d_in[11];
  const float* fc1_w  = (const float*)d_in[12];
  const float* fc1_b  = (const float*)d_in[13];
  const float* fc2_w  = (const float*)d_in[14];
  const float* fc2_b  = (const float*)d_in[15];

  // workspace layout (bytes), M=50176:
  //   [0,            38,535,168)  x2 fp32
  //   [38,535,168,   57,802,752)  hA bf16 (ln1 out / ln2 out; btab overlays)
  //   [57,802,752,  115,605,504)  qkv bf16  --+ dead after proj; hid bf16
  //   [115,605,504, 134,873,088)  attn bf16 --+ overlays [57,802,752, ...)
  //   [173,408,256, 174,587,904)  bf16 weights
  char* ws = (char*)d_ws;
  float* x2   = (float*)(ws + 0);
  u16* hA     = (u16*)(ws + 38535168);
  float* btab = (float*)(ws + 38535168);   // live only qkv->attn
  u16* qkv    = (u16*)(ws + 57802752);
  u16* attn   = (u16*)(ws + 115605504);
  u16* hid    = (u16*)(ws + 57802752);
  u16* wbuf   = (u16*)(ws + 173408256);
  u16* qkv_wb  = wbuf;
  u16* proj_wb = wbuf + 110592;
  u16* fc1_wb  = wbuf + 147456;
  u16* fc2_wb  = wbuf + 368640;

  cast_weights<<<dim3(864), 256, 0, stream>>>(qkv_w, proj_w, fc1_w, fc2_w,
                                              qkv_wb, proj_wb, fc1_wb, fc2_wb);
  ln_kernel<<<dim3(12544), 256, 0, stream>>>(x, ln1_g, ln1_b, hA);
  gemm_kernel<0><<<dim3(392, 6), 256, 0, stream>>>(hA, qkv_wb, qkv_b, nullptr,
                                                   qkv, 576, 192);
  build_btab<<<dim3(96), 256, 0, stream>>>(rpb, btab);
  attn_kernel<<<dim3(1536), 256, 0, stream>>>(qkv, btab, attn);
  gemm_kernel<2><<<dim3(392, 2), 256, 0, stream>>>(attn, proj_wb, proj_b, x,
                                                   x2, 192, 192);
  ln_kernel<<<dim3(12544), 256, 0, stream>>>(x2, ln2_g, ln2_b, hA);
  gemm_kernel<1><<<dim3(392, 12), 256, 0, stream>>>(hA, fc1_wb, fc1_b, nullptr,
                                                    hid, 1152, 192);
  gemm_kernel<2><<<dim3(392, 2), 256, 0, stream>>>(hid, fc2_wb, fc2_b, x2,
                                                   (float*)d_out, 192, 1152);
}